// Round 2
// baseline (1933.170 us; speedup 1.0000x reference)
//
#include <hip/hip_runtime.h>
#include <hip/hip_bf16.h>
#include <math.h>

#define T_LEN 2048
#define BATCH 4
#define DMODEL 256
#define MROWS (BATCH*T_LEN)     // 8192
#define PLANE (MROWS*DMODEL)    // 2,097,152 elements per [B,T,D] plane

typedef __bf16 bf16;
typedef __bf16 bf16x8 __attribute__((ext_vector_type(8)));
typedef float  f32x4  __attribute__((ext_vector_type(4)));

__device__ __forceinline__ void split_bf16(float x, bf16& hi, bf16& lo) {
    hi = (bf16)x;
    lo = (bf16)(x - (float)hi);
}

// ---------------- pack weights: WcatT[n][k] hi/lo (bf16), n in [0,1536) over {q,k,v,gates}
__global__ __launch_bounds__(256) void pack_w(const float* __restrict__ Wq,
                                              const float* __restrict__ Wk,
                                              const float* __restrict__ Wv,
                                              const float* __restrict__ Wg,
                                              bf16* __restrict__ WhT,
                                              bf16* __restrict__ WlT) {
    int n = blockIdx.x;          // 0..1535
    int k = threadIdx.x;         // 0..255
    float v;
    if (n < 256)       v = Wq[k*256 + n];
    else if (n < 512)  v = Wk[k*256 + (n-256)];
    else if (n < 768)  v = Wv[k*256 + (n-512)];
    else               v = Wg[k*768 + (n-768)];
    bf16 h, l; split_bf16(v, h, l);
    WhT[(size_t)n*256 + k] = h;
    WlT[(size_t)n*256 + k] = l;
}

__global__ __launch_bounds__(256) void split_x(const float* __restrict__ x,
                                               bf16* __restrict__ xh,
                                               bf16* __restrict__ xl, int ntot) {
    int i = blockIdx.x*blockDim.x + threadIdx.x;
    int stride = gridDim.x*blockDim.x;
    for (; i < ntot; i += stride) {
        bf16 h, l; split_bf16(x[i], h, l);
        xh[i] = h; xl[i] = l;
    }
}

// ---------------- fused projection GEMM (split-bf16, ~fp32 precision):
// [8192,256] x [256,1536] + per-segment epilogue
__global__ __launch_bounds__(256) void proj_gemm(
    const bf16* __restrict__ xh, const bf16* __restrict__ xl,
    const bf16* __restrict__ WhT, const bf16* __restrict__ WlT,
    const float* __restrict__ bq, const float* __restrict__ bk, const float* __restrict__ bv,
    const float* __restrict__ bg, const float* __restrict__ input_bias,
    float* __restrict__ qP, float* __restrict__ kP, float* __restrict__ vP,
    float* __restrict__ liP, float* __restrict__ lfP, float* __restrict__ soP)
{
    __shared__ bf16 Ah[128*32];
    __shared__ bf16 Al[128*32];
    __shared__ bf16 Bh[128*32];
    __shared__ bf16 Bl[128*32];
    const int tid = threadIdx.x;
    const int w = tid >> 6, l = tid & 63;
    const int wr = w >> 1, wc = w & 1;
    const int m0 = blockIdx.x * 128;
    const int n0 = blockIdx.y * 128;

    f32x4 acc[4][4] = {};

    for (int kt = 0; kt < 256; kt += 32) {
        #pragma unroll
        for (int p = 0; p < 2; ++p) {
            int e = p*2048 + tid*8;                // flat bf16 element in [128][32] tile
            int row = e >> 5, col = e & 31;
            size_t ga = (size_t)(m0 + row)*256 + kt + col;
            size_t gb = (size_t)(n0 + row)*256 + kt + col;
            __builtin_amdgcn_global_load_lds((const __attribute__((address_space(1))) void*)(xh + ga),
                (__attribute__((address_space(3))) void*)(Ah + e), 16, 0, 0);
            __builtin_amdgcn_global_load_lds((const __attribute__((address_space(1))) void*)(xl + ga),
                (__attribute__((address_space(3))) void*)(Al + e), 16, 0, 0);
            __builtin_amdgcn_global_load_lds((const __attribute__((address_space(1))) void*)(WhT + gb),
                (__attribute__((address_space(3))) void*)(Bh + e), 16, 0, 0);
            __builtin_amdgcn_global_load_lds((const __attribute__((address_space(1))) void*)(WlT + gb),
                (__attribute__((address_space(3))) void*)(Bl + e), 16, 0, 0);
        }
        __syncthreads();

        bf16x8 afh[4], afl[4], bfh[4], bfl[4];
        #pragma unroll
        for (int mi = 0; mi < 4; ++mi) {
            int row = wr*64 + mi*16 + (l & 15);
            afh[mi] = *(const bf16x8*)(Ah + row*32 + (l >> 4)*8);
            afl[mi] = *(const bf16x8*)(Al + row*32 + (l >> 4)*8);
        }
        #pragma unroll
        for (int ni = 0; ni < 4; ++ni) {
            int row = wc*64 + ni*16 + (l & 15);
            bfh[ni] = *(const bf16x8*)(Bh + row*32 + (l >> 4)*8);
            bfl[ni] = *(const bf16x8*)(Bl + row*32 + (l >> 4)*8);
        }
        #pragma unroll
        for (int mi = 0; mi < 4; ++mi)
            #pragma unroll
            for (int ni = 0; ni < 4; ++ni) {
                acc[mi][ni] = __builtin_amdgcn_mfma_f32_16x16x32_bf16(afh[mi], bfh[ni], acc[mi][ni], 0, 0, 0);
                acc[mi][ni] = __builtin_amdgcn_mfma_f32_16x16x32_bf16(afh[mi], bfl[ni], acc[mi][ni], 0, 0, 0);
                acc[mi][ni] = __builtin_amdgcn_mfma_f32_16x16x32_bf16(afl[mi], bfh[ni], acc[mi][ni], 0, 0, 0);
            }
        __syncthreads();
    }

    const int seg = n0 >> 8;   // uniform per workgroup: 0=q 1=k 2=v 3=i 4=f 5=o
    #pragma unroll
    for (int mi = 0; mi < 4; ++mi) {
        #pragma unroll
        for (int ni = 0; ni < 4; ++ni) {
            int gcol = n0 + wc*64 + ni*16 + (l & 15);
            int c = gcol & 255;
            #pragma unroll
            for (int r = 0; r < 4; ++r) {
                int grow = m0 + wr*64 + mi*16 + (l >> 4)*4 + r;
                float val = acc[mi][ni][r];
                size_t o = (size_t)grow*256 + c;
                if (seg == 0)      qP[o] = val + bq[c];
                else if (seg == 1) kP[o] = (val + bk[c]) * 0.0625f;     // 1/sqrt(256)
                else if (seg == 2) vP[o] = val + bv[c];
                else if (seg == 3) { float y = val + bg[c] + input_bias[c];
                                     liP[o] = 10.0f * tanhf(y * 0.1f); }
                else if (seg == 4) { float y = val + bg[256 + c];
                                     lfP[o] = -(fmaxf(y, 0.0f) + log1pf(expf(-fabsf(y)))); }
                else               { float y = val + bg[512 + c];
                                     soP[o] = 1.0f / (1.0f + expf(-y)); }
            }
        }
    }
}

// ---------------- sequential scan: 64 wgs/batch, each owns 4 rows of M; state n,m per-d in regs
__global__ __launch_bounds__(256) void scan_kernel(
    const float* __restrict__ qP, const float* __restrict__ kP, const float* __restrict__ vP,
    const float* __restrict__ liP, const float* __restrict__ lfP, const float* __restrict__ soP,
    float* __restrict__ out)
{
    __shared__ float fs_s[256], is_s[256];
    __shared__ __align__(16) float k_s[256], q_s[256];
    __shared__ float vv[4], ov[4], red[4];

    const int tid = threadIdx.x;
    const int w = tid >> 6, l = tid & 63;
    const int b = blockIdx.x >> 6;
    const int r0 = (blockIdx.x & 63) << 2;
    const int myrow = r0 + w;
    const int d = tid;
    const bool own = (d >= r0) && (d < r0 + 4);

    float m_reg = 0.0f, n_reg = 0.0f;   // per-d state (only thread d ever touches it)
    f32x4 M = {0.0f, 0.0f, 0.0f, 0.0f}; // M[myrow][4l..4l+3]

    const size_t base = (size_t)b * T_LEN * 256;

    // preload t=0
    float li_c = liP[base + d];
    float lf_c = lfP[base + d];
    float k_c  = kP[base + d];
    float q_c  = qP[base + d];
    float v_c = 0.0f, o_c = 0.0f;
    if (own) { v_c = vP[base + d]; o_c = soP[base + d]; }

    for (int t = 0; t < T_LEN; ++t) {
        // prefetch t+1 (overlaps with this step's compute)
        float li_n = 0.f, lf_n = 0.f, k_n = 0.f, q_n = 0.f, v_n = 0.f, o_n = 0.f;
        if (t + 1 < T_LEN) {
            size_t nb = base + (size_t)(t + 1) * 256;
            li_n = liP[nb + d]; lf_n = lfP[nb + d];
            k_n  = kP[nb + d];  q_n  = qP[nb + d];
            if (own) { v_n = vP[nb + d]; o_n = soP[nb + d]; }
        }

        // ---- gate phase (thread d handles dimension d) ----
        float m_nx = fmaxf(lf_c + m_reg, li_c);
        float i_s  = expf(li_c - m_nx);
        float f_s  = expf(lf_c + m_reg - m_nx);
        float n_nw = f_s * n_reg + i_s * k_c;
        m_reg = m_nx; n_reg = n_nw;
        fs_s[d] = f_s; is_s[d] = i_s;
        k_s[d] = k_c;  q_s[d] = q_c;
        if (own) { vv[d - r0] = v_c; ov[d - r0] = o_c; }

        float p = n_nw * q_c;                    // denom partial
        #pragma unroll
        for (int s = 32; s; s >>= 1) p += __shfl_xor(p, s);
        if (l == 0) red[w] = p;
        __syncthreads();

        // ---- M phase (wave w owns row myrow; lane l owns cols 4l..4l+3) ----
        float denom = fmaxf(fabsf(red[0] + red[1] + red[2] + red[3]), 1e-6f);
        float fi  = fs_s[myrow];
        float ivi = is_s[myrow] * vv[w];
        f32x4 kk = *(const f32x4*)(k_s + l*4);
        f32x4 qq = *(const f32x4*)(q_s + l*4);
        float h = 0.0f;
        #pragma unroll
        for (int e = 0; e < 4; ++e) {
            M[e] = fi * M[e] + ivi * kk[e];
            h += M[e] * qq[e];
        }
        #pragma unroll
        for (int s = 32; s; s >>= 1) h += __shfl_xor(h, s);
        if (l == 0) out[base + (size_t)t*256 + myrow] = ov[w] * h / denom;
        __syncthreads();   // protect LDS before next step's writes

        li_c = li_n; lf_c = lf_n; k_c = k_n; q_c = q_n; v_c = v_n; o_c = o_n;
    }
}

// ---------------- RMSNorm over d (in-place on out), one wave per (b,t) row
__global__ __launch_bounds__(64) void rmsnorm_kernel(float* __restrict__ out,
                                                     const float* __restrict__ scale) {
    const size_t row = blockIdx.x;
    const int l = threadIdx.x;
    f32x4 h = *(const f32x4*)(out + row*256 + l*4);
    float s = h[0]*h[0] + h[1]*h[1] + h[2]*h[2] + h[3]*h[3];
    #pragma unroll
    for (int sh = 32; sh; sh >>= 1) s += __shfl_xor(s, sh);
    float rinv = rsqrtf(s * (1.0f/256.0f) + 1e-8f);
    f32x4 ns = *(const f32x4*)(scale + l*4);
    f32x4 o;
    #pragma unroll
    for (int e = 0; e < 4; ++e) o[e] = h[e] * rinv * ns[e];
    *(f32x4*)(out + row*256 + l*4) = o;
}

extern "C" void kernel_launch(void* const* d_in, const int* in_sizes, int n_in,
                              void* d_out, int out_size, void* d_ws, size_t ws_size,
                              hipStream_t stream) {
    const float* x          = (const float*)d_in[0];
    const float* Wq         = (const float*)d_in[1];
    const float* bq         = (const float*)d_in[2];
    const float* Wk         = (const float*)d_in[3];
    const float* bk         = (const float*)d_in[4];
    const float* Wv         = (const float*)d_in[5];
    const float* bv         = (const float*)d_in[6];
    const float* Wg         = (const float*)d_in[7];
    const float* bg         = (const float*)d_in[8];
    const float* input_bias = (const float*)d_in[9];
    const float* norm_scale = (const float*)d_in[10];
    float* out = (float*)d_out;

    float* qP  = (float*)d_ws;
    float* kP  = qP  + PLANE;
    float* vP  = kP  + PLANE;
    float* liP = vP  + PLANE;
    float* lfP = liP + PLANE;
    float* soP = lfP + PLANE;
    bf16*  xh  = (bf16*)(soP + PLANE);
    bf16*  xl  = xh + PLANE;
    bf16*  WhT = xl + PLANE;
    bf16*  WlT = WhT + 1536*256;

    pack_w<<<dim3(1536), dim3(256), 0, stream>>>(Wq, Wk, Wv, Wg, WhT, WlT);
    split_x<<<dim3(2048), dim3(256), 0, stream>>>(x, xh, xl, PLANE);
    proj_gemm<<<dim3(64, 12), dim3(256), 0, stream>>>(xh, xl, WhT, WlT, bq, bk, bv, bg, input_bias,
                                                      qP, kP, vP, liP, lfP, soP);
    scan_kernel<<<dim3(256), dim3(256), 0, stream>>>(qP, kP, vP, liP, lfP, soP, out);
    rmsnorm_kernel<<<dim3(MROWS), dim3(64), 0, stream>>>(out, norm_scale);
}

// Round 3
// 1102.577 us; speedup vs baseline: 1.7533x; 1.7533x over previous
//
#include <hip/hip_runtime.h>
#include <hip/hip_bf16.h>
#include <math.h>

#define T_LEN 2048
#define BATCH 4
#define DMODEL 256
#define MROWS (BATCH*T_LEN)     // 8192
#define PLANE (MROWS*DMODEL)    // elements per [B,T,D] plane

#define CH_L 32                 // chunk length
#define NCH  (T_LEN/CH_L)       // 64 chunks
#define RSL  8                  // M rows per workgroup
#define NSL  (DMODEL/RSL)       // 32 slices per batch
#define LSTR 260                // padded LDS row stride (floats)

typedef __bf16 bf16;
typedef __bf16 bf16x8 __attribute__((ext_vector_type(8)));
typedef float  f32x4  __attribute__((ext_vector_type(4)));

__device__ __forceinline__ void split_bf16(float x, bf16& hi, bf16& lo) {
    hi = (bf16)x;
    lo = (bf16)(x - (float)hi);
}

// ---------------- pack weights: WcatT[n][k] hi/lo (bf16), n in [0,1536)
__global__ __launch_bounds__(256) void pack_w(const float* __restrict__ Wq,
                                              const float* __restrict__ Wk,
                                              const float* __restrict__ Wv,
                                              const float* __restrict__ Wg,
                                              bf16* __restrict__ WhT,
                                              bf16* __restrict__ WlT) {
    int n = blockIdx.x;          // 0..1535
    int k = threadIdx.x;         // 0..255
    float v;
    if (n < 256)       v = Wq[k*256 + n];
    else if (n < 512)  v = Wk[k*256 + (n-256)];
    else if (n < 768)  v = Wv[k*256 + (n-512)];
    else               v = Wg[k*768 + (n-768)];
    bf16 h, l; split_bf16(v, h, l);
    WhT[(size_t)n*256 + k] = h;
    WlT[(size_t)n*256 + k] = l;
}

__global__ __launch_bounds__(256) void split_x(const float* __restrict__ x,
                                               bf16* __restrict__ xh,
                                               bf16* __restrict__ xl, int ntot) {
    int i = blockIdx.x*blockDim.x + threadIdx.x;
    int stride = gridDim.x*blockDim.x;
    for (; i < ntot; i += stride) {
        bf16 h, l; split_bf16(x[i], h, l);
        xh[i] = h; xl[i] = l;
    }
}

// ---------------- fused projection GEMM (split-bf16, ~fp32 precision)
__global__ __launch_bounds__(256) void proj_gemm(
    const bf16* __restrict__ xh, const bf16* __restrict__ xl,
    const bf16* __restrict__ WhT, const bf16* __restrict__ WlT,
    const float* __restrict__ bq, const float* __restrict__ bk, const float* __restrict__ bv,
    const float* __restrict__ bg, const float* __restrict__ input_bias,
    float* __restrict__ qP, float* __restrict__ kP, float* __restrict__ vP,
    float* __restrict__ liP, float* __restrict__ lfP, float* __restrict__ soP)
{
    __shared__ bf16 Ah[128*32];
    __shared__ bf16 Al[128*32];
    __shared__ bf16 Bh[128*32];
    __shared__ bf16 Bl[128*32];
    const int tid = threadIdx.x;
    const int w = tid >> 6, l = tid & 63;
    const int wr = w >> 1, wc = w & 1;
    const int m0 = blockIdx.x * 128;
    const int n0 = blockIdx.y * 128;

    f32x4 acc[4][4] = {};

    for (int kt = 0; kt < 256; kt += 32) {
        #pragma unroll
        for (int p = 0; p < 2; ++p) {
            int e = p*2048 + tid*8;
            int row = e >> 5, col = e & 31;
            size_t ga = (size_t)(m0 + row)*256 + kt + col;
            size_t gb = (size_t)(n0 + row)*256 + kt + col;
            __builtin_amdgcn_global_load_lds((const __attribute__((address_space(1))) void*)(xh + ga),
                (__attribute__((address_space(3))) void*)(Ah + e), 16, 0, 0);
            __builtin_amdgcn_global_load_lds((const __attribute__((address_space(1))) void*)(xl + ga),
                (__attribute__((address_space(3))) void*)(Al + e), 16, 0, 0);
            __builtin_amdgcn_global_load_lds((const __attribute__((address_space(1))) void*)(WhT + gb),
                (__attribute__((address_space(3))) void*)(Bh + e), 16, 0, 0);
            __builtin_amdgcn_global_load_lds((const __attribute__((address_space(1))) void*)(WlT + gb),
                (__attribute__((address_space(3))) void*)(Bl + e), 16, 0, 0);
        }
        __syncthreads();

        bf16x8 afh[4], afl[4], bfh[4], bfl[4];
        #pragma unroll
        for (int mi = 0; mi < 4; ++mi) {
            int row = wr*64 + mi*16 + (l & 15);
            afh[mi] = *(const bf16x8*)(Ah + row*32 + (l >> 4)*8);
            afl[mi] = *(const bf16x8*)(Al + row*32 + (l >> 4)*8);
        }
        #pragma unroll
        for (int ni = 0; ni < 4; ++ni) {
            int row = wc*64 + ni*16 + (l & 15);
            bfh[ni] = *(const bf16x8*)(Bh + row*32 + (l >> 4)*8);
            bfl[ni] = *(const bf16x8*)(Bl + row*32 + (l >> 4)*8);
        }
        #pragma unroll
        for (int mi = 0; mi < 4; ++mi)
            #pragma unroll
            for (int ni = 0; ni < 4; ++ni) {
                acc[mi][ni] = __builtin_amdgcn_mfma_f32_16x16x32_bf16(afh[mi], bfh[ni], acc[mi][ni], 0, 0, 0);
                acc[mi][ni] = __builtin_amdgcn_mfma_f32_16x16x32_bf16(afh[mi], bfl[ni], acc[mi][ni], 0, 0, 0);
                acc[mi][ni] = __builtin_amdgcn_mfma_f32_16x16x32_bf16(afl[mi], bfh[ni], acc[mi][ni], 0, 0, 0);
            }
        __syncthreads();
    }

    const int seg = n0 >> 8;
    #pragma unroll
    for (int mi = 0; mi < 4; ++mi) {
        #pragma unroll
        for (int ni = 0; ni < 4; ++ni) {
            int gcol = n0 + wc*64 + ni*16 + (l & 15);
            int c = gcol & 255;
            #pragma unroll
            for (int r = 0; r < 4; ++r) {
                int grow = m0 + wr*64 + mi*16 + (l >> 4)*4 + r;
                float val = acc[mi][ni][r];
                size_t o = (size_t)grow*256 + c;
                if (seg == 0)      qP[o] = val + bq[c];
                else if (seg == 1) kP[o] = (val + bk[c]) * 0.0625f;
                else if (seg == 2) vP[o] = val + bv[c];
                else if (seg == 3) { float y = val + bg[c] + input_bias[c];
                                     liP[o] = 10.0f * tanhf(y * 0.1f); }
                else if (seg == 4) { float y = val + bg[256 + c];
                                     lfP[o] = -(fmaxf(y, 0.0f) + log1pf(expf(-fabsf(y)))); }
                else               { float y = val + bg[512 + c];
                                     soP[o] = 1.0f / (1.0f + expf(-y)); }
            }
        }
    }
}

// ---------------- chunked scan: 128 wgs = 4 batches x 32 row-slices (8 rows each).
// Per chunk (L=32): G=K Q^T via split-bf16 MFMA; elementwise n/m recurrence (exact);
// h = F1*(M0 q) + Ft*(G^T B); M_new = d*M0 + B^T K  (M slice fp32 in registers).
__global__ __launch_bounds__(256) void scan_chunked(
    const float* __restrict__ qP, const float* __restrict__ kP, const float* __restrict__ vP,
    const float* __restrict__ liP, const float* __restrict__ lfP, const float* __restrict__ soP,
    float* __restrict__ out)
{
    __shared__ float K_l[CH_L*LSTR];
    __shared__ float Q_l[CH_L*LSTR];
    __shared__ float lf_l[CH_L*LSTR];
    __shared__ float li_l[CH_L*LSTR];      // aliased as P (= n̂_t q_t) after recurrence
    __shared__ float G_l[CH_L*33];         // G[s][t], padded stride 33
    __shared__ float hpart[CH_L*32];       // [t][il*4 + wave]
    __shared__ float Bm[CH_L*RSL], Uu[CH_L*RSL], MtL[CH_L*RSL];
    __shared__ float F1[CH_L*RSL], Ft[CH_L*RSL];
    __shared__ float Vs[CH_L*RSL], Os[CH_L*RSL];
    __shared__ float denoms[CH_L], th_l[RSL], mps_l[RSL];

    const int tid = threadIdx.x;
    const int w = tid >> 6, l = tid & 63;
    const int b  = blockIdx.x / NSL;
    const int sl = blockIdx.x % NSL;
    const int i0 = sl * RSL;
    const size_t pbase = (size_t)b * T_LEN * DMODEL;

    const int il_m = l >> 3;           // slice-local M row for phases 5a/5b
    const int jg   = l & 7;
    const int j0   = w*64 + jg*8;      // column block owned by this lane

    float Mr[8] = {0.f,0.f,0.f,0.f,0.f,0.f,0.f,0.f};
    float m_st = 0.f, n_st = 0.f;      // per-dim state (thread tid = dim)
    const bool insl = (tid >= i0) && (tid < i0 + RSL);
    const int il_r = tid - i0;

    for (int ch = 0; ch < NCH; ++ch) {
        const int t0 = ch * CH_L;

        // ---- phase 0: stage K,Q,lf,li chunks (+ V,o slices) into LDS ----
        #define STAGE_BUF(PL, LB) \
        { _Pragma("unroll") \
          for (int r8 = 0; r8 < 8; ++r8) { \
              int row = w*8 + r8; \
              const float* src = (PL) + pbase + (size_t)(t0+row)*DMODEL + l*4; \
              float* dst = (LB) + row*LSTR + l*4; \
              __builtin_amdgcn_global_load_lds((const __attribute__((address_space(1))) void*)src, \
                  (__attribute__((address_space(3))) void*)dst, 16, 0, 0); } }
        STAGE_BUF(kP,  K_l)
        STAGE_BUF(qP,  Q_l)
        STAGE_BUF(lfP, lf_l)
        STAGE_BUF(liP, li_l)
        #undef STAGE_BUF
        {
            int r = tid >> 3, cc = tid & 7;
            const float* sv = vP  + pbase + (size_t)(t0+r)*DMODEL + i0 + cc;
            const float* so = soP + pbase + (size_t)(t0+r)*DMODEL + i0 + cc;
            __builtin_amdgcn_global_load_lds((const __attribute__((address_space(1))) void*)sv,
                (__attribute__((address_space(3))) void*)(Vs + r*8 + cc), 4, 0, 0);
            __builtin_amdgcn_global_load_lds((const __attribute__((address_space(1))) void*)so,
                (__attribute__((address_space(3))) void*)(Os + r*8 + cc), 4, 0, 0);
        }
        __syncthreads();

        // ---- phase 1: G = K Q^T (3 of 4 16x16 tiles; tile(1,0) fully masked) ----
        if (w < 3) {
            const int a  = (w == 2) ? 1 : 0;   // s-half
            const int bb = (w == 0) ? 0 : 1;   // t-half
            const int lr = l & 15, lk = l >> 4;
            f32x4 acc = {0.f,0.f,0.f,0.f};
            #pragma unroll
            for (int jj = 0; jj < DMODEL; jj += 32) {
                const float* ka = K_l + (16*a  + lr)*LSTR + jj + lk*8;
                const float* qb = Q_l + (16*bb + lr)*LSTR + jj + lk*8;
                bf16x8 ah, al2, bh, bl2;
                #pragma unroll
                for (int e = 0; e < 8; ++e) {
                    float kv = ka[e]; bf16 kh = (bf16)kv;
                    ah[e] = kh; al2[e] = (bf16)(kv - (float)kh);
                    float qv = qb[e]; bf16 qh = (bf16)qv;
                    bh[e] = qh; bl2[e] = (bf16)(qv - (float)qh);
                }
                acc = __builtin_amdgcn_mfma_f32_16x16x32_bf16(ah,  bh,  acc, 0, 0, 0);
                acc = __builtin_amdgcn_mfma_f32_16x16x32_bf16(ah,  bl2, acc, 0, 0, 0);
                acc = __builtin_amdgcn_mfma_f32_16x16x32_bf16(al2, bh,  acc, 0, 0, 0);
            }
            #pragma unroll
            for (int e = 0; e < 4; ++e)
                G_l[(16*a + lk*4 + e)*33 + 16*bb + lr] = acc[e];
        }

        // ---- phase 2: exact n/m recurrence (thread = dim), write P = n̂·q ----
        if (insl) mps_l[il_r] = m_st;
        {
            float c = 0.f, mloc = m_st, nn = n_st;
            #pragma unroll 4
            for (int t = 0; t < CH_L; ++t) {
                float lfv = lf_l[t*LSTR + tid];
                float liv = li_l[t*LSTR + tid];
                float kv  = K_l[t*LSTR + tid];
                float qv  = Q_l[t*LSTR + tid];
                c += lfv;
                float mn = fmaxf(lfv + mloc, liv);
                float fh = __expf(lfv + mloc - mn);
                float ih = __expf(liv - mn);
                nn = fh*nn + ih*kv;
                mloc = mn;
                li_l[t*LSTR + tid] = nn * qv;            // P
                if (insl) { Uu[t*RSL + il_r] = liv - c; MtL[t*RSL + il_r] = mn - c; }
            }
            m_st = mloc; n_st = nn;
            if (insl) th_l[il_r] = mloc - c;             // theta
        }
        __syncthreads();

        // ---- phase 3+4: denominators (wave-parallel) + B / F1 / Ft ----
        {
            #pragma unroll
            for (int r = 0; r < 8; ++r) {
                int t = w*8 + r;
                f32x4 pv = *(const f32x4*)(li_l + t*LSTR + l*4);
                float s = pv[0]+pv[1]+pv[2]+pv[3];
                #pragma unroll
                for (int sh = 32; sh; sh >>= 1) s += __shfl_xor(s, sh);
                if (l == 0) denoms[t] = fmaxf(fabsf(s), 1e-6f);
            }
            int tt = tid >> 3, ii = tid & 7;
            float th = th_l[ii];
            float Mtv = MtL[tt*RSL + ii];
            Bm[tt*RSL + ii] = __expf(Uu[tt*RSL + ii] - th) * Vs[tt*RSL + ii];
            F1[tt*RSL + ii] = __expf(mps_l[ii] - Mtv);
            Ft[tt*RSL + ii] = __expf(th - Mtv);
        }
        __syncthreads();

        // ---- phase 5a: h_inter partials (lane owns M[i0+il_m][j0..j0+7]) ----
        for (int t = 0; t < CH_L; ++t) {
            const float* qr = Q_l + t*LSTR + j0;
            f32x4 qa = *(const f32x4*)qr;
            f32x4 qb2 = *(const f32x4*)(qr + 4);
            float acc = Mr[0]*qa[0] + Mr[1]*qa[1] + Mr[2]*qa[2] + Mr[3]*qa[3]
                      + Mr[4]*qb2[0] + Mr[5]*qb2[1] + Mr[6]*qb2[2] + Mr[7]*qb2[3];
            acc += __shfl_xor(acc, 1);
            acc += __shfl_xor(acc, 2);
            acc += __shfl_xor(acc, 4);
            if (jg == 0) hpart[t*32 + il_m*4 + w] = acc;
        }
        // ---- phase 5b: M update: M = d*M0 + B^T K ----
        {
            float dd = __expf(mps_l[il_m] - th_l[il_m]);
            #pragma unroll
            for (int e = 0; e < 8; ++e) Mr[e] *= dd;
            for (int s = 0; s < CH_L; ++s) {
                float Bv = Bm[s*RSL + il_m];
                const float* kr = K_l + s*LSTR + j0;
                f32x4 ka = *(const f32x4*)kr;
                f32x4 kb2 = *(const f32x4*)(kr + 4);
                Mr[0] += Bv*ka[0];  Mr[1] += Bv*ka[1];
                Mr[2] += Bv*ka[2];  Mr[3] += Bv*ka[3];
                Mr[4] += Bv*kb2[0]; Mr[5] += Bv*kb2[1];
                Mr[6] += Bv*kb2[2]; Mr[7] += Bv*kb2[3];
            }
        }
        __syncthreads();

        // ---- phase 6: intra term + combine + store ----
        {
            int t = tid >> 3, ii = tid & 7;
            float intra = 0.f;
            #pragma unroll 4
            for (int s = 0; s <= t; ++s)
                intra += G_l[s*33 + t] * Bm[s*RSL + ii];
            float inter = hpart[t*32 + ii*4 + 0] + hpart[t*32 + ii*4 + 1]
                        + hpart[t*32 + ii*4 + 2] + hpart[t*32 + ii*4 + 3];
            float h = F1[t*RSL + ii]*inter + Ft[t*RSL + ii]*intra;
            float res = Os[t*RSL + ii] * h / denoms[t];
            out[pbase + (size_t)(t0 + t)*DMODEL + i0 + ii] = res;
        }
        __syncthreads();
    }
}

// ---------------- RMSNorm over d (in-place on out), one wave per (b,t) row
__global__ __launch_bounds__(64) void rmsnorm_kernel(float* __restrict__ out,
                                                     const float* __restrict__ scale) {
    const size_t row = blockIdx.x;
    const int l = threadIdx.x;
    f32x4 h = *(const f32x4*)(out + row*256 + l*4);
    float s = h[0]*h[0] + h[1]*h[1] + h[2]*h[2] + h[3]*h[3];
    #pragma unroll
    for (int sh = 32; sh; sh >>= 1) s += __shfl_xor(s, sh);
    float rinv = rsqrtf(s * (1.0f/256.0f) + 1e-8f);
    f32x4 ns = *(const f32x4*)(scale + l*4);
    f32x4 o;
    #pragma unroll
    for (int e = 0; e < 4; ++e) o[e] = h[e] * rinv * ns[e];
    *(f32x4*)(out + row*256 + l*4) = o;
}

extern "C" void kernel_launch(void* const* d_in, const int* in_sizes, int n_in,
                              void* d_out, int out_size, void* d_ws, size_t ws_size,
                              hipStream_t stream) {
    const float* x          = (const float*)d_in[0];
    const float* Wq         = (const float*)d_in[1];
    const float* bq         = (const float*)d_in[2];
    const float* Wk         = (const float*)d_in[3];
    const float* bk         = (const float*)d_in[4];
    const float* Wv         = (const float*)d_in[5];
    const float* bv         = (const float*)d_in[6];
    const float* Wg         = (const float*)d_in[7];
    const float* bg         = (const float*)d_in[8];
    const float* input_bias = (const float*)d_in[9];
    const float* norm_scale = (const float*)d_in[10];
    float* out = (float*)d_out;

    float* qP  = (float*)d_ws;
    float* kP  = qP  + PLANE;
    float* vP  = kP  + PLANE;
    float* liP = vP  + PLANE;
    float* lfP = liP + PLANE;
    float* soP = lfP + PLANE;
    bf16*  xh  = (bf16*)(soP + PLANE);
    bf16*  xl  = xh + PLANE;
    bf16*  WhT = xl + PLANE;
    bf16*  WlT = WhT + 1536*256;

    pack_w<<<dim3(1536), dim3(256), 0, stream>>>(Wq, Wk, Wv, Wg, WhT, WlT);
    split_x<<<dim3(2048), dim3(256), 0, stream>>>(x, xh, xl, PLANE);
    proj_gemm<<<dim3(64, 12), dim3(256), 0, stream>>>(xh, xl, WhT, WlT, bq, bk, bv, bg, input_bias,
                                                      qP, kP, vP, liP, lfP, soP);
    scan_chunked<<<dim3(BATCH*NSL), dim3(256), 0, stream>>>(qP, kP, vP, liP, lfP, soP, out);
    rmsnorm_kernel<<<dim3(MROWS), dim3(64), 0, stream>>>(out, norm_scale);
}

// Round 4
// 177.668 us; speedup vs baseline: 10.8808x; 6.2058x over previous
//
#include <hip/hip_runtime.h>
#include <hip/hip_bf16.h>
#include <math.h>

#define T_LEN 2048
#define BATCH 4
#define DMODEL 256
#define MROWS (BATCH*T_LEN)
#define PLANE (MROWS*DMODEL)
#define CH_L 32
#define NCH  (T_LEN/CH_L)          // 64
#define SUMSZ (BATCH*NCH*DMODEL)   // 65536
#define MSLOT (DMODEL*DMODEL)      // 65536

typedef __bf16 bf16;
typedef __bf16 bf16x8 __attribute__((ext_vector_type(8)));
typedef float  f32x4  __attribute__((ext_vector_type(4)));
typedef unsigned short u16;
typedef u16 u16x8 __attribute__((ext_vector_type(8)));
typedef unsigned int u32;
typedef u32 u32x4 __attribute__((ext_vector_type(4)));

#define MFMA(a,b,c) __builtin_amdgcn_mfma_f32_16x16x32_bf16(a, b, c, 0, 0, 0)

__device__ __forceinline__ void split_bf16(float x, bf16& hi, bf16& lo) {
    hi = (bf16)x;
    lo = (bf16)(x - (float)hi);
}

__device__ __forceinline__ float pack_split_f(float x) {
    bf16 h, l; split_bf16(x, h, l);
    union { bf16 b; u16 u; } a, b2; a.b = h; b2.b = l;
    u32 v = (u32)a.u | ((u32)b2.u << 16);
    return __builtin_bit_cast(float, v);
}

__device__ __forceinline__ float bflo(u32 v) { union { u16 u; bf16 b; } c; c.u = (u16)(v & 0xffffu); return (float)c.b; }
__device__ __forceinline__ float bfhi(u32 v) { union { u16 u; bf16 b; } c; c.u = (u16)(v >> 16); return (float)c.b; }

__device__ __forceinline__ void split8(const float* p, bf16x8& h, bf16x8& l) {
    f32x4 a = *(const f32x4*)p;
    f32x4 b = *(const f32x4*)(p + 4);
    #pragma unroll
    for (int e = 0; e < 4; ++e) {
        bf16 hh, ll;
        split_bf16(a[e], hh, ll); h[e] = hh; l[e] = ll;
        split_bf16(b[e], hh, ll); h[4+e] = hh; l[4+e] = ll;
    }
}

#define GLD16(SRC, DST) __builtin_amdgcn_global_load_lds( \
    (const __attribute__((address_space(1))) void*)(SRC), \
    (__attribute__((address_space(3))) void*)(DST), 16, 0, 0)

// ---------------- pack weights: WcatT[n][k] hi/lo (bf16), n in [0,1536)
__global__ __launch_bounds__(256) void pack_w(const float* __restrict__ Wq,
                                              const float* __restrict__ Wk,
                                              const float* __restrict__ Wv,
                                              const float* __restrict__ Wg,
                                              bf16* __restrict__ WhT,
                                              bf16* __restrict__ WlT) {
    int n = blockIdx.x;
    int k = threadIdx.x;
    float v;
    if (n < 256)       v = Wq[k*256 + n];
    else if (n < 512)  v = Wk[k*256 + (n-256)];
    else if (n < 768)  v = Wv[k*256 + (n-512)];
    else               v = Wg[k*768 + (n-768)];
    bf16 h, l; split_bf16(v, h, l);
    WhT[(size_t)n*256 + k] = h;
    WlT[(size_t)n*256 + k] = l;
}

__global__ __launch_bounds__(256) void split_x(const float* __restrict__ x,
                                               bf16* __restrict__ xh,
                                               bf16* __restrict__ xl, int ntot) {
    int i = blockIdx.x*blockDim.x + threadIdx.x;
    int stride = gridDim.x*blockDim.x;
    for (; i < ntot; i += stride) {
        bf16 h, l; split_bf16(x[i], h, l);
        xh[i] = h; xl[i] = l;
    }
}

// ---------------- fused projection GEMM (split-bf16, ~fp32 precision)
__global__ __launch_bounds__(256) void proj_gemm(
    const bf16* __restrict__ xh, const bf16* __restrict__ xl,
    const bf16* __restrict__ WhT, const bf16* __restrict__ WlT,
    const float* __restrict__ bq, const float* __restrict__ bk, const float* __restrict__ bv,
    const float* __restrict__ bg, const float* __restrict__ input_bias,
    float* __restrict__ qP, float* __restrict__ kP, float* __restrict__ vP,
    float* __restrict__ liP, float* __restrict__ lfP, float* __restrict__ soP)
{
    __shared__ bf16 Ah[128*32];
    __shared__ bf16 Al[128*32];
    __shared__ bf16 Bh[128*32];
    __shared__ bf16 Bl[128*32];
    const int tid = threadIdx.x;
    const int w = tid >> 6, l = tid & 63;
    const int wr = w >> 1, wc = w & 1;
    const int m0 = blockIdx.x * 128;
    const int n0 = blockIdx.y * 128;

    f32x4 acc[4][4] = {};

    for (int kt = 0; kt < 256; kt += 32) {
        #pragma unroll
        for (int p = 0; p < 2; ++p) {
            int e = p*2048 + tid*8;
            int row = e >> 5, col = e & 31;
            size_t ga = (size_t)(m0 + row)*256 + kt + col;
            size_t gb = (size_t)(n0 + row)*256 + kt + col;
            GLD16(xh + ga, Ah + e);
            GLD16(xl + ga, Al + e);
            GLD16(WhT + gb, Bh + e);
            GLD16(WlT + gb, Bl + e);
        }
        __syncthreads();

        bf16x8 afh[4], afl[4], bfh[4], bfl[4];
        #pragma unroll
        for (int mi = 0; mi < 4; ++mi) {
            int row = wr*64 + mi*16 + (l & 15);
            afh[mi] = *(const bf16x8*)(Ah + row*32 + (l >> 4)*8);
            afl[mi] = *(const bf16x8*)(Al + row*32 + (l >> 4)*8);
        }
        #pragma unroll
        for (int ni = 0; ni < 4; ++ni) {
            int row = wc*64 + ni*16 + (l & 15);
            bfh[ni] = *(const bf16x8*)(Bh + row*32 + (l >> 4)*8);
            bfl[ni] = *(const bf16x8*)(Bl + row*32 + (l >> 4)*8);
        }
        #pragma unroll
        for (int mi = 0; mi < 4; ++mi)
            #pragma unroll
            for (int ni = 0; ni < 4; ++ni) {
                acc[mi][ni] = MFMA(afh[mi], bfh[ni], acc[mi][ni]);
                acc[mi][ni] = MFMA(afh[mi], bfl[ni], acc[mi][ni]);
                acc[mi][ni] = MFMA(afl[mi], bfh[ni], acc[mi][ni]);
            }
        __syncthreads();
    }

    const int seg = n0 >> 8;
    #pragma unroll
    for (int mi = 0; mi < 4; ++mi) {
        #pragma unroll
        for (int ni = 0; ni < 4; ++ni) {
            int gcol = n0 + wc*64 + ni*16 + (l & 15);
            int c = gcol & 255;
            #pragma unroll
            for (int r = 0; r < 4; ++r) {
                int grow = m0 + wr*64 + mi*16 + (l >> 4)*4 + r;
                float val = acc[mi][ni][r];
                size_t o = (size_t)grow*256 + c;
                if (seg == 0)      qP[o] = val + bq[c];
                else if (seg == 1) kP[o] = (val + bk[c]) * 0.0625f;
                else if (seg == 2) vP[o] = val + bv[c];
                else if (seg == 3) { float y = val + bg[c] + input_bias[c];
                                     liP[o] = 10.0f * tanhf(y * 0.1f); }
                else if (seg == 4) { float y = val + bg[256 + c];
                                     lfP[o] = -(fmaxf(y, 0.0f) + log1pf(expf(-fabsf(y)))); }
                else               { float y = val + bg[512 + c];
                                     soP[o] = 1.0f / (1.0f + expf(-y)); }
            }
        }
    }
}

// ---------------- chunk summaries: per (b,c,j): C = sum lf; mu = max(li - Cpref); Bn
__global__ __launch_bounds__(256) void chunk_summary(
    const float* __restrict__ lfP, const float* __restrict__ liP, const float* __restrict__ kP,
    float* __restrict__ Csum, float* __restrict__ Mu, float* __restrict__ Bn)
{
    const int b = blockIdx.x >> 6, c = blockIdx.x & 63;
    const int j = threadIdx.x;
    const size_t base = ((size_t)b*T_LEN + (size_t)c*CH_L)*DMODEL + j;
    float C = 0.f, mu = -3e38f;
    float val[CH_L];
    #pragma unroll
    for (int s = 0; s < CH_L; ++s) {
        C += lfP[base + (size_t)s*DMODEL];
        val[s] = liP[base + (size_t)s*DMODEL] - C;
        mu = fmaxf(mu, val[s]);
    }
    float bn = 0.f;
    #pragma unroll
    for (int s = 0; s < CH_L; ++s)
        bn += __expf(val[s] - mu) * kP[base + (size_t)s*DMODEL];
    size_t o = ((size_t)b*NCH + c)*DMODEL + j;
    Csum[o] = C; Mu[o] = mu; Bn[o] = bn;
}

// ---------------- sequential compose of (m,n) boundary states across 64 chunks (tiny)
__global__ __launch_bounds__(256) void chunk_compose(
    const float* __restrict__ Csum, const float* __restrict__ Mu, const float* __restrict__ Bn,
    float* __restrict__ mIn, float* __restrict__ nIn, float* __restrict__ Th,
    float* __restrict__ Dd)
{
    const int b = blockIdx.x;
    const int j = threadIdx.x;
    float m = 0.f, n = 0.f;
    for (int c = 0; c < NCH; ++c) {
        size_t o = ((size_t)b*NCH + c)*DMODEL + j;
        mIn[o] = m; nIn[o] = n;
        float cs = Csum[o], mu = Mu[o], bn = Bn[o];
        float th = fmaxf(m, mu);
        Th[o] = th;
        float d = __expf(m - th);
        Dd[o] = d;
        n = d*n + __expf(mu - th)*bn;
        m = cs + th;
    }
}

// ---------------- Delta-M per chunk: DM[b,c] = Bhat^T K  (256x256, MFMA)
__global__ __launch_bounds__(256) void s2_dm(
    const float* __restrict__ kP, const float* __restrict__ vP,
    const float* __restrict__ liP, const float* __restrict__ lfP,
    const float* __restrict__ Th, float* __restrict__ DM)
{
    __shared__ bf16 BTh[DMODEL][40], BTl[DMODEL][40];
    __shared__ bf16 KTh[DMODEL][40], KTl[DMODEL][40];
    const int tid = threadIdx.x;
    const int w = tid >> 6, l = tid & 63;
    const int b = blockIdx.x >> 6, c = blockIdx.x & 63;
    const size_t pb = ((size_t)b*T_LEN + (size_t)c*CH_L)*DMODEL;

    {
        const float thL = Th[((size_t)b*NCH + c)*DMODEL + tid];
        float C = 0.f;
        #pragma unroll
        for (int s = 0; s < CH_L; ++s) {
            size_t o = pb + (size_t)s*DMODEL + tid;
            float lf = lfP[o], li = liP[o], vv = vP[o], kv = kP[o];
            C += lf;
            float bv = __expf(li - C - thL) * vv;
            bf16 h, lo; split_bf16(bv, h, lo);
            BTh[tid][s] = h; BTl[tid][s] = lo;
            bf16 kh, kl; split_bf16(kv, kh, kl);
            KTh[tid][s] = kh; KTl[tid][s] = kl;
        }
    }
    __syncthreads();

    const int lr = l & 15, lk = l >> 4;
    bf16x8 Ah[4], Al[4];
    #pragma unroll
    for (int it = 0; it < 4; ++it) {
        int row = w*64 + it*16 + lr;
        Ah[it] = *(const bf16x8*)&BTh[row][lk*8];
        Al[it] = *(const bf16x8*)&BTl[row][lk*8];
    }
    float* DMc = DM + (size_t)((size_t)b*NCH + c)*MSLOT;
    #pragma unroll
    for (int jt = 0; jt < 16; ++jt) {
        int jcol = jt*16 + lr;
        bf16x8 bh = *(const bf16x8*)&KTh[jcol][lk*8];
        bf16x8 bl = *(const bf16x8*)&KTl[jcol][lk*8];
        #pragma unroll
        for (int it = 0; it < 4; ++it) {
            f32x4 a = {0.f,0.f,0.f,0.f};
            a = MFMA(Ah[it], bh, a);
            a = MFMA(Al[it], bh, a);
            a = MFMA(Ah[it], bl, a);
            #pragma unroll
            for (int r = 0; r < 4; ++r)
                DMc[(size_t)(w*64 + it*16 + lk*4 + r)*DMODEL + jcol] = a[r];
        }
    }
}

// ---------------- compose M across chunks per (b,i,j); write boundary states packed-split in-place
__global__ __launch_bounds__(256) void s3_compose(
    const float* __restrict__ Dd, float* __restrict__ DM)
{
    const int b = blockIdx.x >> 8, i = blockIdx.x & 255;
    const int j = threadIdx.x;
    float acc = 0.f;
    const size_t base = ((size_t)b*NCH)*MSLOT + (size_t)i*DMODEL + j;
    for (int c = 0; c < NCH; ++c) {
        size_t a = base + (size_t)c*MSLOT;
        float dm = DM[a];
        if (c > 0) DM[a] = pack_split_f(acc);
        float d = Dd[((size_t)b*NCH + c)*DMODEL + i];
        acc = d*acc + dm;
    }
}

// ---------------- per-chunk output: H = F1*(Q Mprev^T) + Bt*(Gm^T Bhat); fused sigma(o)/denom
__global__ __launch_bounds__(256) void s4_chunk(
    const float* __restrict__ qP, const float* __restrict__ kP, const float* __restrict__ vP,
    const float* __restrict__ liP, const float* __restrict__ lfP, const float* __restrict__ soP,
    const float* __restrict__ mIn, const float* __restrict__ nIn, const float* __restrict__ Th,
    const float* __restrict__ DM, float* __restrict__ out)
{
    __shared__ float Kf[CH_L][268];
    __shared__ float Qf[CH_L][268];
    __shared__ float Pbuf[CH_L][260];     // aliased later as packed scales
    __shared__ bf16 BTh[DMODEL][40];
    __shared__ float GT[CH_L][44];
    __shared__ float denoms[CH_L];

    const int tid = threadIdx.x;
    const int w = tid >> 6, l = tid & 63;
    const int b = blockIdx.x >> 6;
    const int c = blockIdx.x & 63;
    const size_t pb = ((size_t)b*T_LEN + (size_t)c*CH_L)*DMODEL;

    // phase 0: stage K,Q fp32 rows into LDS
    #pragma unroll
    for (int r8 = 0; r8 < 8; ++r8) {
        int row = w*8 + r8;
        GLD16(kP + pb + (size_t)row*DMODEL + l*4, &Kf[row][l*4]);
        GLD16(qP + pb + (size_t)row*DMODEL + l*4, &Qf[row][l*4]);
    }

    // phase 1: per-dim recurrences (thread = dim)
    const int i = tid;
    const size_t cbx = ((size_t)b*NCH + c)*DMODEL + i;
    const float thL = Th[cbx];
    const float mI = mIn[cbx];
    float th_arr[CH_L];
    {
        float C = 0.f, mu = -3e38f, n = nIn[cbx], thp = mI;
        #pragma unroll
        for (int t = 0; t < CH_L; ++t) {
            size_t o = pb + (size_t)t*DMODEL + i;
            float lf = lfP[o], li = liP[o], kv = kP[o], qv = qP[o], vv = vP[o];
            C += lf;
            float vlc = li - C;
            mu = fmaxf(mu, vlc);
            float tht = fmaxf(mI, mu);
            th_arr[t] = tht;
            float f = __expf(thp - tht);
            float iv = __expf(vlc - tht);
            n = f*n + iv*kv;
            thp = tht;
            Pbuf[t][i] = n * qv;
            BTh[i][t] = (bf16)(__expf(vlc - thL) * vv);
        }
    }
    __syncthreads();

    // phase 2: denominators
    #pragma unroll
    for (int r = 0; r < 8; ++r) {
        int t = w*8 + r;
        f32x4 pv = *(const f32x4*)&Pbuf[t][l*4];
        float s = pv[0]+pv[1]+pv[2]+pv[3];
        #pragma unroll
        for (int sh = 32; sh; sh >>= 1) s += __shfl_xor(s, sh);
        if (l == 0) denoms[t] = fmaxf(fabsf(s), 1e-6f);
    }
    __syncthreads();

    // phase 3a: packed scales (F1, Bt) -> alias over Pbuf
    u32 (*scl)[260] = (u32(*)[260])Pbuf;
    #pragma unroll
    for (int t = 0; t < CH_L; ++t) {
        float F1 = __expf(mI - th_arr[t]);
        float Bt = __expf(thL - th_arr[t]);
        union { bf16 b; u16 u; } a1, a2; a1.b = (bf16)F1; a2.b = (bf16)Bt;
        scl[t][i] = (u32)a1.u | ((u32)a2.u << 16);
    }
    // phase 3b: G = K Q^T, one 16x16 tile per wave, masked write transposed
    {
        const int srow = (w & 1)*16, tcol = (w >> 1)*16;
        const int lr = l & 15, lk2 = l >> 4;
        f32x4 g = {0.f,0.f,0.f,0.f};
        #pragma unroll
        for (int ks = 0; ks < 8; ++ks) {
            bf16x8 ah, al, bh, bl;
            split8(&Kf[srow + lr][ks*32 + lk2*8], ah, al);
            split8(&Qf[tcol + lr][ks*32 + lk2*8], bh, bl);
            g = MFMA(ah, bh, g);
            g = MFMA(al, bh, g);
            g = MFMA(ah, bl, g);
        }
        #pragma unroll
        for (int r = 0; r < 4; ++r) {
            int s = srow + lk2*4 + r, t = tcol + lr;
            GT[t][s] = (s <= t) ? g[r] : 0.f;
        }
    }
    __syncthreads();

    // phase 4: output GEMMs. wave -> (t-half tt, 8 i-tiles)
    const int tt = w & 1;
    const int lr = l & 15, lk2 = l >> 4;
    const int trow = tt*16 + lr;
    f32x4 acc_a[8], acc_b[8];

    {   // intra: Gm^T Bhat  (K-dim = 32 = chunk)
        bf16x8 gh, gl;
        split8(&GT[trow][lk2*8], gh, gl);
        #pragma unroll
        for (int it = 0; it < 8; ++it) {
            int irow = ((w>>1)*8 + it)*16 + lr;
            bf16x8 bb = *(const bf16x8*)&BTh[irow][lk2*8];
            f32x4 a = {0.f,0.f,0.f,0.f};
            a = MFMA(gh, bb, a);
            a = MFMA(gl, bb, a);
            acc_a[it] = a;
        }
    }
    #pragma unroll
    for (int it = 0; it < 8; ++it) acc_b[it] = (f32x4){0.f,0.f,0.f,0.f};
    if (c > 0) {   // inter: Q Mprev^T, Mprev streamed packed-split from global
        const u32* Mbase = (const u32*)DM + (size_t)((size_t)b*NCH + c)*MSLOT;
        #pragma unroll
        for (int ks = 0; ks < 8; ++ks) {
            bf16x8 qh, ql;
            split8(&Qf[trow][ks*32 + lk2*8], qh, ql);
            #pragma unroll
            for (int it = 0; it < 8; ++it) {
                int irow = ((w>>1)*8 + it)*16 + lr;
                const u32* mp = Mbase + (size_t)irow*DMODEL + ks*32 + lk2*8;
                u32x4 ma = *(const u32x4*)mp;
                u32x4 mb = *(const u32x4*)(mp + 4);
                union { u16x8 u; bf16x8 h; } Mh, Ml;
                #pragma unroll
                for (int e = 0; e < 4; ++e) {
                    Mh.u[e]   = (u16)(ma[e] & 0xffffu); Ml.u[e]   = (u16)(ma[e] >> 16);
                    Mh.u[4+e] = (u16)(mb[e] & 0xffffu); Ml.u[4+e] = (u16)(mb[e] >> 16);
                }
                f32x4 a = acc_b[it];
                a = MFMA(qh, Mh.h, a);
                a = MFMA(ql, Mh.h, a);
                a = MFMA(qh, Ml.h, a);
                acc_b[it] = a;
            }
        }
    }
    // epilogue
    #pragma unroll
    for (int it = 0; it < 8; ++it) {
        int icol = ((w>>1)*8 + it)*16 + lr;
        #pragma unroll
        for (int r = 0; r < 4; ++r) {
            int t = tt*16 + lk2*4 + r;
            u32 sc = scl[t][icol];
            float h = bflo(sc)*acc_b[it][r] + bfhi(sc)*acc_a[it][r];
            size_t o = pb + (size_t)t*DMODEL + icol;
            out[o] = soP[o] * h / denoms[t];
        }
    }
}

// ---------------- RMSNorm over d (in-place on out), one wave per (b,t) row
__global__ __launch_bounds__(64) void rmsnorm_kernel(float* __restrict__ out,
                                                     const float* __restrict__ scale) {
    const size_t row = blockIdx.x;
    const int l = threadIdx.x;
    f32x4 h = *(const f32x4*)(out + row*256 + l*4);
    float s = h[0]*h[0] + h[1]*h[1] + h[2]*h[2] + h[3]*h[3];
    #pragma unroll
    for (int sh = 32; sh; sh >>= 1) s += __shfl_xor(s, sh);
    float rinv = rsqrtf(s * (1.0f/256.0f) + 1e-8f);
    f32x4 ns = *(const f32x4*)(scale + l*4);
    f32x4 o;
    #pragma unroll
    for (int e = 0; e < 4; ++e) o[e] = h[e] * rinv * ns[e];
    *(f32x4*)(out + row*256 + l*4) = o;
}

extern "C" void kernel_launch(void* const* d_in, const int* in_sizes, int n_in,
                              void* d_out, int out_size, void* d_ws, size_t ws_size,
                              hipStream_t stream) {
    const float* x          = (const float*)d_in[0];
    const float* Wq         = (const float*)d_in[1];
    const float* bq         = (const float*)d_in[2];
    const float* Wk         = (const float*)d_in[3];
    const float* bk         = (const float*)d_in[4];
    const float* Wv         = (const float*)d_in[5];
    const float* bv         = (const float*)d_in[6];
    const float* Wg         = (const float*)d_in[7];
    const float* bg         = (const float*)d_in[8];
    const float* input_bias = (const float*)d_in[9];
    const float* norm_scale = (const float*)d_in[10];
    float* out = (float*)d_out;

    float* qP   = (float*)d_ws;
    float* kP   = qP  + PLANE;
    float* vP   = kP  + PLANE;
    float* liP  = vP  + PLANE;
    float* lfP  = liP + PLANE;
    float* soP  = lfP + PLANE;
    float* Csum = soP + PLANE;
    float* Mu   = Csum + SUMSZ;
    float* Bn   = Mu   + SUMSZ;
    float* mIn  = Bn   + SUMSZ;
    float* nIn  = mIn  + SUMSZ;
    float* Th   = nIn  + SUMSZ;
    float* Dd   = Th   + SUMSZ;
    float* DM   = Dd   + SUMSZ;                       // 4*64*65536 floats = 64 MiB
    bf16*  xh   = (bf16*)(DM + (size_t)BATCH*NCH*MSLOT);
    bf16*  xl   = xh + PLANE;
    bf16*  WhT  = xl + PLANE;
    bf16*  WlT  = WhT + 1536*256;

    pack_w<<<dim3(1536), dim3(256), 0, stream>>>(Wq, Wk, Wv, Wg, WhT, WlT);
    split_x<<<dim3(2048), dim3(256), 0, stream>>>(x, xh, xl, PLANE);
    proj_gemm<<<dim3(64, 12), dim3(256), 0, stream>>>(xh, xl, WhT, WlT, bq, bk, bv, bg, input_bias,
                                                      qP, kP, vP, liP, lfP, soP);
    chunk_summary<<<dim3(BATCH*NCH), dim3(256), 0, stream>>>(lfP, liP, kP, Csum, Mu, Bn);
    chunk_compose<<<dim3(BATCH), dim3(256), 0, stream>>>(Csum, Mu, Bn, mIn, nIn, Th, Dd);
    s2_dm<<<dim3(BATCH*NCH), dim3(256), 0, stream>>>(kP, vP, liP, lfP, Th, DM);
    s3_compose<<<dim3(BATCH*256), dim3(256), 0, stream>>>(Dd, DM);
    s4_chunk<<<dim3(BATCH*NCH), dim3(256), 0, stream>>>(qP, kP, vP, liP, lfP, soP,
                                                        mIn, nIn, Th, DM, out);
    rmsnorm_kernel<<<dim3(MROWS), dim3(64), 0, stream>>>(out, norm_scale);
}

// Round 5
// 146.295 us; speedup vs baseline: 13.2142x; 1.2144x over previous
//
#include <hip/hip_runtime.h>
#include <hip/hip_bf16.h>
#include <math.h>

#define T_LEN 2048
#define BATCH 4
#define DMODEL 256
#define MROWS (BATCH*T_LEN)
#define PLANE (MROWS*DMODEL)
#define CH_L 32
#define NCH  (T_LEN/CH_L)          // 64
#define SUMSZ (BATCH*NCH*DMODEL)   // 65536
#define MSLOT (DMODEL*DMODEL)      // 65536

typedef __bf16 bf16;
typedef __bf16 bf16x8 __attribute__((ext_vector_type(8)));
typedef float  f32x4  __attribute__((ext_vector_type(4)));
typedef unsigned short u16;
typedef u16 u16x8 __attribute__((ext_vector_type(8)));
typedef unsigned int u32;
typedef u32 u32x4 __attribute__((ext_vector_type(4)));

#define MFMA(a,b,c) __builtin_amdgcn_mfma_f32_16x16x32_bf16(a, b, c, 0, 0, 0)

__device__ __forceinline__ void split_bf16(float x, bf16& hi, bf16& lo) {
    hi = (bf16)x;
    lo = (bf16)(x - (float)hi);
}

__device__ __forceinline__ float pack_split_f(float x) {
    bf16 h, l; split_bf16(x, h, l);
    union { bf16 b; u16 u; } a, b2; a.b = h; b2.b = l;
    u32 v = (u32)a.u | ((u32)b2.u << 16);
    return __builtin_bit_cast(float, v);
}

__device__ __forceinline__ float bflo(u32 v) { union { u16 u; bf16 b; } c; c.u = (u16)(v & 0xffffu); return (float)c.b; }
__device__ __forceinline__ float bfhi(u32 v) { union { u16 u; bf16 b; } c; c.u = (u16)(v >> 16); return (float)c.b; }

__device__ __forceinline__ void split8(const float* p, bf16x8& h, bf16x8& l) {
    f32x4 a = *(const f32x4*)p;
    f32x4 b = *(const f32x4*)(p + 4);
    #pragma unroll
    for (int e = 0; e < 4; ++e) {
        bf16 hh, ll;
        split_bf16(a[e], hh, ll); h[e] = hh; l[e] = ll;
        split_bf16(b[e], hh, ll); h[4+e] = hh; l[4+e] = ll;
    }
}

// fast transcendentals (hardware v_exp_f32 based)
__device__ __forceinline__ float tanh_fast(float z) {
    z = fminf(fmaxf(z, -15.f), 15.f);
    float e = __expf(2.f * z);
    return (e - 1.f) / (e + 1.f);
}
__device__ __forceinline__ float nsoftplus_fast(float y) {   // -softplus(y)
    return -(fmaxf(y, 0.f) + __logf(1.f + __expf(-fabsf(y))));
}
__device__ __forceinline__ float sigmoid_fast(float y) {
    return 1.f / (1.f + __expf(-y));
}

#define GLD16(SRC, DST) __builtin_amdgcn_global_load_lds( \
    (const __attribute__((address_space(1))) void*)(SRC), \
    (__attribute__((address_space(3))) void*)(DST), 16, 0, 0)

// ---------------- pack weights: WcatT[n][k] hi/lo (bf16), n in [0,1536)
__global__ __launch_bounds__(256) void pack_w(const float* __restrict__ Wq,
                                              const float* __restrict__ Wk,
                                              const float* __restrict__ Wv,
                                              const float* __restrict__ Wg,
                                              bf16* __restrict__ WhT,
                                              bf16* __restrict__ WlT) {
    int n = blockIdx.x;
    int k = threadIdx.x;
    float v;
    if (n < 256)       v = Wq[k*256 + n];
    else if (n < 512)  v = Wk[k*256 + (n-256)];
    else if (n < 768)  v = Wv[k*256 + (n-512)];
    else               v = Wg[k*768 + (n-768)];
    bf16 h, l; split_bf16(v, h, l);
    WhT[(size_t)n*256 + k] = h;
    WlT[(size_t)n*256 + k] = l;
}

// ---------------- fused projection GEMM: fp32 A staged + in-reg split, dbuf pipeline,
// XOR-swizzled LDS, fast-math epilogue. [8192,256] x [256,1536].
__global__ __launch_bounds__(256) void proj_gemm(
    const float* __restrict__ x,
    const bf16* __restrict__ WhT, const bf16* __restrict__ WlT,
    const float* __restrict__ bq, const float* __restrict__ bk, const float* __restrict__ bv,
    const float* __restrict__ bg, const float* __restrict__ input_bias,
    float* __restrict__ qP, float* __restrict__ kP, float* __restrict__ vP,
    float* __restrict__ liP, float* __restrict__ lfP, float* __restrict__ soP)
{
    __shared__ float Axf[2][128*32];     // fp32 A tile, 16B-block col-swizzle cb^(row&7)
    __shared__ bf16  Bhs[2][128*32];     // bf16 B tiles, 16B-block col-swizzle cb^((row>>1)&3)
    __shared__ bf16  Bls[2][128*32];
    const int tid = threadIdx.x;
    const int w = tid >> 6, l = tid & 63;
    const int wr = w >> 1, wc = w & 1;
    const int m0 = blockIdx.x * 128;
    const int n0 = blockIdx.y * 128;

    f32x4 acc[4][4] = {};

    #define STAGE(BUF, KT) { \
        _Pragma("unroll") \
        for (int p = 0; p < 4; ++p) { \
            int row = p*32 + (tid >> 3); \
            int cbd = tid & 7; \
            int scol = ((cbd ^ (row & 7)) << 2) + (KT); \
            GLD16(x + (size_t)(m0 + row)*256 + scol, &Axf[BUF][p*1024 + tid*4]); \
        } \
        _Pragma("unroll") \
        for (int p = 0; p < 2; ++p) { \
            int row = p*64 + (tid >> 2); \
            int cbd = tid & 3; \
            int scol = ((cbd ^ ((row >> 1) & 3)) << 3) + (KT); \
            size_t so = (size_t)(n0 + row)*256 + scol; \
            GLD16(WhT + so, &Bhs[BUF][p*2048 + tid*8]); \
            GLD16(WlT + so, &Bls[BUF][p*2048 + tid*8]); \
        } }

    STAGE(0, 0)
    __syncthreads();

    const int lk = l >> 4;               // 0..3 (k-group)
    #pragma unroll
    for (int ki = 0; ki < 8; ++ki) {
        const int cur = ki & 1;
        if (ki < 7) STAGE(cur ^ 1, (ki+1)*32)

        bf16x8 afh[4], afl[4];
        #pragma unroll
        for (int mi = 0; mi < 4; ++mi) {
            int row = wr*64 + mi*16 + (l & 15);
            int cb0 = lk*2;
            const float* base = &Axf[cur][row*32];
            f32x4 a0 = *(const f32x4*)(base + (((cb0  ) ^ (row & 7)) << 2));
            f32x4 a1 = *(const f32x4*)(base + (((cb0+1) ^ (row & 7)) << 2));
            #pragma unroll
            for (int e = 0; e < 4; ++e) {
                bf16 h, lo;
                split_bf16(a0[e], h, lo); afh[mi][e]   = h; afl[mi][e]   = lo;
                split_bf16(a1[e], h, lo); afh[mi][4+e] = h; afl[mi][4+e] = lo;
            }
        }
        #pragma unroll
        for (int ni = 0; ni < 4; ++ni) {
            int row = wc*64 + ni*16 + (l & 15);
            int blk = lk ^ ((row >> 1) & 3);
            bf16x8 bh = *(const bf16x8*)&Bhs[cur][row*32 + blk*8];
            bf16x8 bl = *(const bf16x8*)&Bls[cur][row*32 + blk*8];
            #pragma unroll
            for (int mi = 0; mi < 4; ++mi) {
                acc[mi][ni] = MFMA(afh[mi], bh, acc[mi][ni]);
                acc[mi][ni] = MFMA(afl[mi], bh, acc[mi][ni]);
                acc[mi][ni] = MFMA(afh[mi], bl, acc[mi][ni]);
            }
        }
        __syncthreads();
    }

    const int seg = n0 >> 8;   // 0=q 1=k 2=v 3=i 4=f 5=o (uniform per wg)
    #pragma unroll
    for (int mi = 0; mi < 4; ++mi) {
        #pragma unroll
        for (int ni = 0; ni < 4; ++ni) {
            int gcol = n0 + wc*64 + ni*16 + (l & 15);
            int c = gcol & 255;
            #pragma unroll
            for (int r = 0; r < 4; ++r) {
                int grow = m0 + wr*64 + mi*16 + (l >> 4)*4 + r;
                float val = acc[mi][ni][r];
                size_t o = (size_t)grow*256 + c;
                if (seg == 0)      qP[o] = val + bq[c];
                else if (seg == 1) kP[o] = (val + bk[c]) * 0.0625f;
                else if (seg == 2) vP[o] = val + bv[c];
                else if (seg == 3) { float y = val + bg[c] + input_bias[c];
                                     liP[o] = 10.0f * tanh_fast(y * 0.1f); }
                else if (seg == 4) { float y = val + bg[256 + c];
                                     lfP[o] = nsoftplus_fast(y); }
                else               { float y = val + bg[512 + c];
                                     soP[o] = sigmoid_fast(y); }
            }
        }
    }
    #undef STAGE
}

// ---------------- chunk summaries: per (b,c,j): C = sum lf; mu = max(li - Cpref); Bn
__global__ __launch_bounds__(256) void chunk_summary(
    const float* __restrict__ lfP, const float* __restrict__ liP, const float* __restrict__ kP,
    float* __restrict__ Csum, float* __restrict__ Mu, float* __restrict__ Bn)
{
    const int b = blockIdx.x >> 6, c = blockIdx.x & 63;
    const int j = threadIdx.x;
    const size_t base = ((size_t)b*T_LEN + (size_t)c*CH_L)*DMODEL + j;
    float C = 0.f, mu = -3e38f;
    float val[CH_L];
    #pragma unroll
    for (int s = 0; s < CH_L; ++s) {
        C += lfP[base + (size_t)s*DMODEL];
        val[s] = liP[base + (size_t)s*DMODEL] - C;
        mu = fmaxf(mu, val[s]);
    }
    float bn = 0.f;
    #pragma unroll
    for (int s = 0; s < CH_L; ++s)
        bn += __expf(val[s] - mu) * kP[base + (size_t)s*DMODEL];
    size_t o = ((size_t)b*NCH + c)*DMODEL + j;
    Csum[o] = C; Mu[o] = mu; Bn[o] = bn;
}

// ---------------- sequential compose of (m,n) boundary states across 64 chunks (tiny)
__global__ __launch_bounds__(256) void chunk_compose(
    const float* __restrict__ Csum, const float* __restrict__ Mu, const float* __restrict__ Bn,
    float* __restrict__ mIn, float* __restrict__ nIn, float* __restrict__ Th,
    float* __restrict__ Dd)
{
    const int b = blockIdx.x;
    const int j = threadIdx.x;
    float m = 0.f, n = 0.f;
    for (int c = 0; c < NCH; ++c) {
        size_t o = ((size_t)b*NCH + c)*DMODEL + j;
        mIn[o] = m; nIn[o] = n;
        float cs = Csum[o], mu = Mu[o], bn = Bn[o];
        float th = fmaxf(m, mu);
        Th[o] = th;
        float d = __expf(m - th);
        Dd[o] = d;
        n = d*n + __expf(mu - th)*bn;
        m = cs + th;
    }
}

// ---------------- Delta-M per chunk: DM[b,c] = Bhat^T K  (256x256, MFMA)
__global__ __launch_bounds__(256) void s2_dm(
    const float* __restrict__ kP, const float* __restrict__ vP,
    const float* __restrict__ liP, const float* __restrict__ lfP,
    const float* __restrict__ Th, float* __restrict__ DM)
{
    __shared__ bf16 BTh[DMODEL][40], BTl[DMODEL][40];
    __shared__ bf16 KTh[DMODEL][40], KTl[DMODEL][40];
    const int tid = threadIdx.x;
    const int w = tid >> 6, l = tid & 63;
    const int b = blockIdx.x >> 6, c = blockIdx.x & 63;
    const size_t pb = ((size_t)b*T_LEN + (size_t)c*CH_L)*DMODEL;

    {
        const float thL = Th[((size_t)b*NCH + c)*DMODEL + tid];
        float C = 0.f;
        #pragma unroll
        for (int s = 0; s < CH_L; ++s) {
            size_t o = pb + (size_t)s*DMODEL + tid;
            float lf = lfP[o], li = liP[o], vv = vP[o], kv = kP[o];
            C += lf;
            float bv = __expf(li - C - thL) * vv;
            bf16 h, lo; split_bf16(bv, h, lo);
            BTh[tid][s] = h; BTl[tid][s] = lo;
            bf16 kh, kl; split_bf16(kv, kh, kl);
            KTh[tid][s] = kh; KTl[tid][s] = kl;
        }
    }
    __syncthreads();

    const int lr = l & 15, lk = l >> 4;
    bf16x8 Ah[4], Al[4];
    #pragma unroll
    for (int it = 0; it < 4; ++it) {
        int row = w*64 + it*16 + lr;
        Ah[it] = *(const bf16x8*)&BTh[row][lk*8];
        Al[it] = *(const bf16x8*)&BTl[row][lk*8];
    }
    float* DMc = DM + (size_t)((size_t)b*NCH + c)*MSLOT;
    #pragma unroll
    for (int jt = 0; jt < 16; ++jt) {
        int jcol = jt*16 + lr;
        bf16x8 bh = *(const bf16x8*)&KTh[jcol][lk*8];
        bf16x8 bl = *(const bf16x8*)&KTl[jcol][lk*8];
        #pragma unroll
        for (int it = 0; it < 4; ++it) {
            f32x4 a = {0.f,0.f,0.f,0.f};
            a = MFMA(Ah[it], bh, a);
            a = MFMA(Al[it], bh, a);
            a = MFMA(Ah[it], bl, a);
            #pragma unroll
            for (int r = 0; r < 4; ++r)
                DMc[(size_t)(w*64 + it*16 + lk*4 + r)*DMODEL + jcol] = a[r];
        }
    }
}

// ---------------- compose M across chunks per (b,i,j); write boundary states packed-split in-place
__global__ __launch_bounds__(256) void s3_compose(
    const float* __restrict__ Dd, float* __restrict__ DM)
{
    const int b = blockIdx.x >> 8, i = blockIdx.x & 255;
    const int j = threadIdx.x;
    float acc = 0.f;
    const size_t base = ((size_t)b*NCH)*MSLOT + (size_t)i*DMODEL + j;
    for (int c = 0; c < NCH; ++c) {
        size_t a = base + (size_t)c*MSLOT;
        float dm = DM[a];
        if (c > 0) DM[a] = pack_split_f(acc);
        float d = Dd[((size_t)b*NCH + c)*DMODEL + i];
        acc = d*acc + dm;
    }
}

// ---------------- per-chunk output + fused RMSNorm:
// H = F1*(Q Mprev^T) + Bt*(Gm^T Bhat); h = sigma(o)*H/denom; out = h/rms * scale
__global__ __launch_bounds__(256) void s4_chunk(
    const float* __restrict__ qP, const float* __restrict__ kP, const float* __restrict__ vP,
    const float* __restrict__ liP, const float* __restrict__ lfP, const float* __restrict__ soP,
    const float* __restrict__ mIn, const float* __restrict__ nIn, const float* __restrict__ Th,
    const float* __restrict__ DM, const float* __restrict__ norm_scale,
    float* __restrict__ out)
{
    __shared__ float Kf[CH_L][268];
    __shared__ float Qf[CH_L][268];       // aliased as Hout in the epilogue
    __shared__ float Pbuf[CH_L][260];     // aliased as packed scales
    __shared__ bf16 BTh[DMODEL][40];
    __shared__ float GT[CH_L][44];
    __shared__ float denoms[CH_L];

    const int tid = threadIdx.x;
    const int w = tid >> 6, l = tid & 63;
    const int b = blockIdx.x >> 6;
    const int c = blockIdx.x & 63;
    const size_t pb = ((size_t)b*T_LEN + (size_t)c*CH_L)*DMODEL;

    // phase 0: stage K,Q fp32 rows into LDS (completes under phase 1)
    #pragma unroll
    for (int r8 = 0; r8 < 8; ++r8) {
        int row = w*8 + r8;
        GLD16(kP + pb + (size_t)row*DMODEL + l*4, &Kf[row][l*4]);
        GLD16(qP + pb + (size_t)row*DMODEL + l*4, &Qf[row][l*4]);
    }

    // phase 1: per-dim recurrences (thread = dim)
    const int i = tid;
    const size_t cbx = ((size_t)b*NCH + c)*DMODEL + i;
    const float thL = Th[cbx];
    const float mI = mIn[cbx];
    float th_arr[CH_L];
    {
        float C = 0.f, mu = -3e38f, n = nIn[cbx], thp = mI;
        #pragma unroll
        for (int t = 0; t < CH_L; ++t) {
            size_t o = pb + (size_t)t*DMODEL + i;
            float lf = lfP[o], li = liP[o], kv = kP[o], qv = qP[o], vv = vP[o];
            C += lf;
            float vlc = li - C;
            mu = fmaxf(mu, vlc);
            float tht = fmaxf(mI, mu);
            th_arr[t] = tht;
            float f = __expf(thp - tht);
            float iv = __expf(vlc - tht);
            n = f*n + iv*kv;
            thp = tht;
            Pbuf[t][i] = n * qv;
            BTh[i][t] = (bf16)(__expf(vlc - thL) * vv);
        }
    }
    __syncthreads();

    // phase 2: denominators
    #pragma unroll
    for (int r = 0; r < 8; ++r) {
        int t = w*8 + r;
        f32x4 pv = *(const f32x4*)&Pbuf[t][l*4];
        float s = pv[0]+pv[1]+pv[2]+pv[3];
        #pragma unroll
        for (int sh = 32; sh; sh >>= 1) s += __shfl_xor(s, sh);
        if (l == 0) denoms[t] = fmaxf(fabsf(s), 1e-6f);
    }
    __syncthreads();

    // phase 3a: packed scales (F1, Bt) -> alias over Pbuf
    u32 (*scl)[260] = (u32(*)[260])Pbuf;
    #pragma unroll
    for (int t = 0; t < CH_L; ++t) {
        float F1 = __expf(mI - th_arr[t]);
        float Bt = __expf(thL - th_arr[t]);
        union { bf16 b; u16 u; } a1, a2; a1.b = (bf16)F1; a2.b = (bf16)Bt;
        scl[t][i] = (u32)a1.u | ((u32)a2.u << 16);
    }
    // phase 3b: G = K Q^T, one 16x16 tile per wave, masked write transposed
    {
        const int srow = (w & 1)*16, tcol = (w >> 1)*16;
        const int lr = l & 15, lk2 = l >> 4;
        f32x4 g = {0.f,0.f,0.f,0.f};
        #pragma unroll
        for (int ks = 0; ks < 8; ++ks) {
            bf16x8 ah, al, bh, bl;
            split8(&Kf[srow + lr][ks*32 + lk2*8], ah, al);
            split8(&Qf[tcol + lr][ks*32 + lk2*8], bh, bl);
            g = MFMA(ah, bh, g);
            g = MFMA(al, bh, g);
            g = MFMA(ah, bl, g);
        }
        #pragma unroll
        for (int r = 0; r < 4; ++r) {
            int s = srow + lk2*4 + r, t = tcol + lr;
            GT[t][s] = (s <= t) ? g[r] : 0.f;
        }
    }
    __syncthreads();

    // phase 4: output GEMMs. wave -> (t-half tt, 8 i-tiles)
    const int tt = w & 1;
    const int lr = l & 15, lk2 = l >> 4;
    const int trow = tt*16 + lr;
    f32x4 acc_a[8], acc_b[8];

    {   // intra: Gm^T Bhat  (K-dim = 32 = chunk)
        bf16x8 gh, gl;
        split8(&GT[trow][lk2*8], gh, gl);
        #pragma unroll
        for (int it = 0; it < 8; ++it) {
            int irow = ((w>>1)*8 + it)*16 + lr;
            bf16x8 bb = *(const bf16x8*)&BTh[irow][lk2*8];
            f32x4 a = {0.f,0.f,0.f,0.f};
            a = MFMA(gh, bb, a);
            a = MFMA(gl, bb, a);
            acc_a[it] = a;
        }
    }
    #pragma unroll
    for (int it = 0; it < 8; ++it) acc_b[it] = (f32x4){0.f,0.f,0.f,0.f};
    if (c > 0) {   // inter: Q Mprev^T, Mprev streamed packed-split from global
        const u32* Mbase = (const u32*)DM + (size_t)((size_t)b*NCH + c)*MSLOT;
        #pragma unroll
        for (int ks = 0; ks < 8; ++ks) {
            bf16x8 qh, ql;
            split8(&Qf[trow][ks*32 + lk2*8], qh, ql);
            #pragma unroll
            for (int it = 0; it < 8; ++it) {
                int irow = ((w>>1)*8 + it)*16 + lr;
                const u32* mp = Mbase + (size_t)irow*DMODEL + ks*32 + lk2*8;
                u32x4 ma = *(const u32x4*)mp;
                u32x4 mb = *(const u32x4*)(mp + 4);
                union { u16x8 u; bf16x8 h; } Mh, Ml;
                #pragma unroll
                for (int e = 0; e < 4; ++e) {
                    Mh.u[e]   = (u16)(ma[e] & 0xffffu); Ml.u[e]   = (u16)(ma[e] >> 16);
                    Mh.u[4+e] = (u16)(mb[e] & 0xffffu); Ml.u[4+e] = (u16)(mb[e] >> 16);
                }
                f32x4 a = acc_b[it];
                a = MFMA(qh, Mh.h, a);
                a = MFMA(ql, Mh.h, a);
                a = MFMA(qh, Ml.h, a);
                acc_b[it] = a;
            }
        }
    }
    // epilogue part 1: combine into pre-norm h, park in LDS (alias Qf after all reads done)
    __syncthreads();
    float* Hout = &Qf[0][0];             // [32][268]
    #pragma unroll
    for (int it = 0; it < 8; ++it) {
        int icol = ((w>>1)*8 + it)*16 + lr;
        #pragma unroll
        for (int r = 0; r < 4; ++r) {
            int t = tt*16 + lk2*4 + r;
            u32 sc = scl[t][icol];
            float h = bflo(sc)*acc_b[it][r] + bfhi(sc)*acc_a[it][r];
            size_t o = pb + (size_t)t*DMODEL + icol;
            Hout[t*268 + icol] = soP[o] * h / denoms[t];
        }
    }
    __syncthreads();
    // epilogue part 2: fused RMSNorm (wave w owns rows w*8..w*8+7), coalesced stores
    #pragma unroll
    for (int r = 0; r < 8; ++r) {
        int t = w*8 + r;
        f32x4 hv = *(const f32x4*)&Hout[t*268 + l*4];
        float ss = hv[0]*hv[0] + hv[1]*hv[1] + hv[2]*hv[2] + hv[3]*hv[3];
        #pragma unroll
        for (int sh = 32; sh; sh >>= 1) ss += __shfl_xor(ss, sh);
        float rinv = rsqrtf(ss * (1.0f/256.0f) + 1e-8f);
        f32x4 ns = *(const f32x4*)(norm_scale + l*4);
        f32x4 o4;
        #pragma unroll
        for (int e = 0; e < 4; ++e) o4[e] = hv[e] * rinv * ns[e];
        *(f32x4*)(out + pb + (size_t)t*DMODEL + l*4) = o4;
    }
}

extern "C" void kernel_launch(void* const* d_in, const int* in_sizes, int n_in,
                              void* d_out, int out_size, void* d_ws, size_t ws_size,
                              hipStream_t stream) {
    const float* x          = (const float*)d_in[0];
    const float* Wq         = (const float*)d_in[1];
    const float* bq         = (const float*)d_in[2];
    const float* Wk         = (const float*)d_in[3];
    const float* bk         = (const float*)d_in[4];
    const float* Wv         = (const float*)d_in[5];
    const float* bv         = (const float*)d_in[6];
    const float* Wg         = (const float*)d_in[7];
    const float* bg         = (const float*)d_in[8];
    const float* input_bias = (const float*)d_in[9];
    const float* norm_scale = (const float*)d_in[10];
    float* out = (float*)d_out;

    float* qP   = (float*)d_ws;
    float* kP   = qP  + PLANE;
    float* vP   = kP  + PLANE;
    float* liP  = vP  + PLANE;
    float* lfP  = liP + PLANE;
    float* soP  = lfP + PLANE;
    float* Csum = soP + PLANE;
    float* Mu   = Csum + SUMSZ;
    float* Bn   = Mu   + SUMSZ;
    float* mIn  = Bn   + SUMSZ;
    float* nIn  = mIn  + SUMSZ;
    float* Th   = nIn  + SUMSZ;
    float* Dd   = Th   + SUMSZ;
    float* DM   = Dd   + SUMSZ;                       // 4*64*65536 floats = 64 MiB
    bf16*  WhT  = (bf16*)(DM + (size_t)BATCH*NCH*MSLOT);
    bf16*  WlT  = WhT + 1536*256;

    pack_w<<<dim3(1536), dim3(256), 0, stream>>>(Wq, Wk, Wv, Wg, WhT, WlT);
    proj_gemm<<<dim3(64, 12), dim3(256), 0, stream>>>(x, WhT, WlT, bq, bk, bv, bg, input_bias,
                                                      qP, kP, vP, liP, lfP, soP);
    chunk_summary<<<dim3(BATCH*NCH), dim3(256), 0, stream>>>(lfP, liP, kP, Csum, Mu, Bn);
    chunk_compose<<<dim3(BATCH), dim3(256), 0, stream>>>(Csum, Mu, Bn, mIn, nIn, Th, Dd);
    s2_dm<<<dim3(BATCH*NCH), dim3(256), 0, stream>>>(kP, vP, liP, lfP, Th, DM);
    s3_compose<<<dim3(BATCH*256), dim3(256), 0, stream>>>(Dd, DM);
    s4_chunk<<<dim3(BATCH*NCH), dim3(256), 0, stream>>>(qP, kP, vP, liP, lfP, soP,
                                                        mIn, nIn, Th, DM, norm_scale, out);
}